// Round 1
// baseline (84765.045 us; speedup 1.0000x reference)
//
#include <hip/hip_runtime.h>
#include <hip/hip_bf16.h>

// ESN forward: states[s] = tanh(x[s] @ W_in^T + b + h_{s-1} @ W_hh^T)
// SEQ=1024, BATCH=64, IN=512, RES=2048, all fp32 in/out.
// Strategy: fp16 MFMA (fp32 accum) everywhere; W_hh resident in LDS (persistent
// kernel, 1 block/CU); per-step sync via flag barrier scoped to independent
// batch-groups (16 batches each) mapped onto XCD pairs.

#define SEQ 1024
#define NB  64
#define INF 512
#define RES 2048

typedef float    f32x4 __attribute__((ext_vector_type(4)));
typedef _Float16 f16x8 __attribute__((ext_vector_type(8)));

// ---------------------------------------------------------------------------
// Kernel B: U = X @ Win^T + bias   (M=65536, N=2048, K=512), U -> d_out states
// 128x128 tile, BK=32, 256 threads (4 waves, 64x64 wave tile), dbuf LDS,
// reg-staged fp32->fp16 conversion.
// ---------------------------------------------------------------------------
__global__ __launch_bounds__(256) void xin_gemm(
    const float* __restrict__ X, const float* __restrict__ Win,
    const float* __restrict__ bias, float* __restrict__ U)
{
  __shared__ _Float16 lA[2][128][40];   // +8 half pad -> 80B row stride, 2-way banks (free)
  __shared__ _Float16 lB[2][128][40];

  const int tid  = threadIdx.x;
  const int lane = tid & 63;
  const int wv   = tid >> 6;
  const int wr   = wv >> 1;            // wave row 0..1
  const int wc   = wv & 1;             // wave col 0..1
  const int m0   = (blockIdx.x >> 4) * 128;  // n-tile fastest: 16 consecutive bids share A panel
  const int n0   = (blockIdx.x & 15) * 128;

  const int srow = tid >> 1;           // staging row 0..127
  const int sk   = (tid & 1) * 16;     // staging k half 0/16

  const int fr = lane & 15;            // fragment row/col
  const int fk = (lane >> 4) * 8;      // fragment k offset

  f32x4 acc[4][4] = {};
  float ra[16], rb[16];

  const float* xa_base = X   + (size_t)(m0 + srow) * INF + sk;
  const float* xb_base = Win + (size_t)(n0 + srow) * INF + sk;

#define LOADK(kt) do {                                                     \
    const float* pa = xa_base + (kt) * 32;                                 \
    const float* pb = xb_base + (kt) * 32;                                 \
    *(f32x4*)&ra[0]  = *(const f32x4*)(pa + 0);                            \
    *(f32x4*)&ra[4]  = *(const f32x4*)(pa + 4);                            \
    *(f32x4*)&ra[8]  = *(const f32x4*)(pa + 8);                            \
    *(f32x4*)&ra[12] = *(const f32x4*)(pa + 12);                           \
    *(f32x4*)&rb[0]  = *(const f32x4*)(pb + 0);                            \
    *(f32x4*)&rb[4]  = *(const f32x4*)(pb + 4);                            \
    *(f32x4*)&rb[8]  = *(const f32x4*)(pb + 8);                            \
    *(f32x4*)&rb[12] = *(const f32x4*)(pb + 12);                           \
  } while (0)

#define STOREK(buf) do {                                                   \
    f16x8 h0, h1;                                                          \
    _Pragma("unroll") for (int j = 0; j < 8; ++j) h0[j] = (_Float16)ra[j]; \
    _Pragma("unroll") for (int j = 0; j < 8; ++j) h1[j] = (_Float16)ra[8+j];\
    *(f16x8*)&lA[buf][srow][sk]     = h0;                                  \
    *(f16x8*)&lA[buf][srow][sk + 8] = h1;                                  \
    _Pragma("unroll") for (int j = 0; j < 8; ++j) h0[j] = (_Float16)rb[j]; \
    _Pragma("unroll") for (int j = 0; j < 8; ++j) h1[j] = (_Float16)rb[8+j];\
    *(f16x8*)&lB[buf][srow][sk]     = h0;                                  \
    *(f16x8*)&lB[buf][srow][sk + 8] = h1;                                  \
  } while (0)

#define COMPUTE(buf) do {                                                  \
    f16x8 af[4], bf[4];                                                    \
    _Pragma("unroll") for (int mt = 0; mt < 4; ++mt)                       \
      af[mt] = *(const f16x8*)&lA[buf][wr*64 + mt*16 + fr][fk];            \
    _Pragma("unroll") for (int nt = 0; nt < 4; ++nt)                       \
      bf[nt] = *(const f16x8*)&lB[buf][wc*64 + nt*16 + fr][fk];            \
    _Pragma("unroll") for (int mt = 0; mt < 4; ++mt)                       \
      _Pragma("unroll") for (int nt = 0; nt < 4; ++nt)                     \
        acc[mt][nt] = __builtin_amdgcn_mfma_f32_16x16x32_f16(              \
            af[mt], bf[nt], acc[mt][nt], 0, 0, 0);                         \
  } while (0)

  LOADK(0);
  STOREK(0);
  __syncthreads();

#pragma unroll 1
  for (int kt = 0; kt < 16; ++kt) {
    const int buf = kt & 1;
    if (kt < 15) LOADK(kt + 1);
    COMPUTE(buf);
    if (kt < 15) STOREK(buf ^ 1);
    __syncthreads();
  }

#pragma unroll
  for (int mt = 0; mt < 4; ++mt) {
    const int row = m0 + wr*64 + mt*16 + (lane >> 4) * 4;
#pragma unroll
    for (int nt = 0; nt < 4; ++nt) {
      const int col = n0 + wc*64 + nt*16 + fr;
      const float bv = bias[col];
#pragma unroll
      for (int i = 0; i < 4; ++i)
        U[(size_t)(row + i) * RES + col] = acc[mt][nt][i] + bv;
    }
  }
#undef LOADK
#undef STOREK
#undef COMPUTE
}

// ---------------------------------------------------------------------------
// Kernel C: persistent recurrence. 256 blocks x 512 threads, 1 block/CU.
// Block = (batch-group bg of 16 batches) x (col-group cg of 32 res columns).
// W_hh rows [c0,c0+32) live in LDS fp16 (padded stride kills bank conflicts).
// 8 waves: wave = (col-tile ct 0..1) x (k-quarter q 0..3); LDS tree-reduce.
// Per-step sync: flag barrier scoped to the 64 WGs of a batch-group (groups
// are fully independent). bid swizzle puts a group on one XCD pair.
// ---------------------------------------------------------------------------
#define WPAD 2056   // 2048 + 8 halfs pad -> row stride 4112B, 2-way banks

__global__ __launch_bounds__(512, 1) void esn_recur(
    const float* __restrict__ Whh, float* __restrict__ states,
    float* __restrict__ hn, _Float16* __restrict__ hbuf,
    unsigned* __restrict__ flags)
{
  __shared__ _Float16 Wl[32 * WPAD];   // 128.5 KB
  __shared__ f32x4    red[6][64];      // 6 KB reduction scratch

  const int tid  = threadIdx.x;
  const int lane = tid & 63;
  const int wv   = tid >> 6;      // 0..7
  const int ct   = wv & 1;        // col tile within WG
  const int q    = wv >> 1;       // k quarter 0..3

  const int bid = blockIdx.x;
  const int xg  = bid & 7;                        // ~XCD id under %8 round-robin
  const int bg  = xg >> 1;                        // batch group 0..3 -> XCD pair
  const int cg  = ((xg & 1) << 5) | (bid >> 3);   // col group 0..63 (bijective)
  const int b0  = bg * 16;
  const int c0  = cg * 32;

  // one-time: W_hh rows [c0, c0+32) -> LDS fp16
  {
    const int row = tid >> 4;     // 0..31
    const int ch  = tid & 15;     // 0..15
    const float* src = Whh + (size_t)(c0 + row) * RES + ch * 128;
    _Float16* dst = Wl + row * WPAD + ch * 128;
#pragma unroll 4
    for (int i = 0; i < 128; i += 4) {
      f32x4 v = *(const f32x4*)(src + i);
      dst[i + 0] = (_Float16)v.x;
      dst[i + 1] = (_Float16)v.y;
      dst[i + 2] = (_Float16)v.z;
      dst[i + 3] = (_Float16)v.w;
    }
  }
  __syncthreads();

  const int fr = lane & 15;
  const int fk = (lane >> 4) * 8;

  _Float16* const hbuf0 = hbuf;
  _Float16* const hbuf1 = hbuf + (size_t)NB * RES;
  unsigned* const gflags = flags + bg * 64;

  const _Float16* const wp = Wl + (ct*16 + fr) * WPAD + q*512 + fk;

  for (int s = 0; s < SEQ; ++s) {
    f32x4 acc0 = {0.f, 0.f, 0.f, 0.f}, acc1 = {0.f, 0.f, 0.f, 0.f};
    if (s > 0) {
      // h_{s-1} lives in hbuf[(s-1)&1]
      const _Float16* hp = ((s & 1) ? hbuf0 : hbuf1)
                         + (size_t)(b0 + fr) * RES + q*512 + fk;
#pragma unroll
      for (int ks = 0; ks < 16; ks += 2) {
        f16x8 a0 = *(const f16x8*)(hp + ks*32);
        f16x8 w0 = *(const f16x8*)(wp + ks*32);
        f16x8 a1 = *(const f16x8*)(hp + ks*32 + 32);
        f16x8 w1 = *(const f16x8*)(wp + ks*32 + 32);
        acc0 = __builtin_amdgcn_mfma_f32_16x16x32_f16(a0, w0, acc0, 0, 0, 0);
        acc1 = __builtin_amdgcn_mfma_f32_16x16x32_f16(a1, w1, acc1, 0, 0, 0);
      }
    }
    f32x4 acc = acc0 + acc1;

    if (q > 0) red[ct*3 + (q - 1)][lane] = acc;
    __syncthreads();

    if (q == 0) {
      acc += red[ct*3 + 0][lane];
      acc += red[ct*3 + 1][lane];
      acc += red[ct*3 + 2][lane];
      float* up = states + (size_t)s * NB * RES;
      _Float16* hc = (s & 1) ? hbuf1 : hbuf0;
      const int col = c0 + ct*16 + fr;
#pragma unroll
      for (int i = 0; i < 4; ++i) {
        const int b = b0 + (lane >> 4) * 4 + i;
        const size_t off = (size_t)b * RES + col;
        const float v = tanhf(up[off] + acc[i]);
        up[off] = v;                          // states[s] (u overwritten by h_s)
        hc[off] = (_Float16)v;                // fp16 copy for next step's MFMA
        if (s == SEQ - 1) hn[off] = v;        // final hidden state output
      }
    }

    // release: make h_s visible device-wide, then raise our flag
    __threadfence();
    __syncthreads();
    if (tid == 0)
      __hip_atomic_store(&gflags[cg], (unsigned)(s + 1),
                         __ATOMIC_RELEASE, __HIP_MEMORY_SCOPE_AGENT);
    // wave 0: each lane spins on one producer flag of our batch group
    if (tid < 64) {
      while (__hip_atomic_load(&gflags[tid], __ATOMIC_RELAXED,
                               __HIP_MEMORY_SCOPE_AGENT) <= (unsigned)s) { }
    }
    __syncthreads();
    __threadfence();   // acquire: invalidate L1 before reading remote h_s
  }
}

// ---------------------------------------------------------------------------
extern "C" void kernel_launch(void* const* d_in, const int* in_sizes, int n_in,
                              void* d_out, int out_size, void* d_ws, size_t ws_size,
                              hipStream_t stream) {
  const float* x    = (const float*)d_in[0];   // [1024][64][512]
  const float* W_in = (const float*)d_in[1];   // [2048][512]
  const float* W_hh = (const float*)d_in[2];   // [2048][2048]
  const float* bias = (const float*)d_in[3];   // [2048]

  float* states = (float*)d_out;                        // [1024][64][2048]
  float* hn     = states + (size_t)SEQ * NB * RES;      // [64][2048]

  _Float16* hbuf  = (_Float16*)d_ws;                    // 2 x [64][2048] fp16
  unsigned* flags = (unsigned*)((char*)d_ws + (size_t)2 * NB * RES * sizeof(_Float16));

  hipMemsetAsync(flags, 0, 256 * sizeof(unsigned), stream);

  xin_gemm<<<dim3(512 * 16), dim3(256), 0, stream>>>(x, W_in, bias, states);
  esn_recur<<<dim3(256), dim3(512), 0, stream>>>(W_hh, states, hn, hbuf, flags);
}

// Round 2
// 7564.861 us; speedup vs baseline: 11.2051x; 11.2051x over previous
//
#include <hip/hip_runtime.h>
#include <hip/hip_bf16.h>

// ESN forward: states[s] = tanh(x[s] @ W_in^T + b + h_{s-1} @ W_hh^T)
// SEQ=1024, BATCH=64, IN=512, RES=2048, all fp32 in/out.
// fp16 MFMA; W_hh resident in LDS (persistent kernel, 1 WG/CU).
// Cross-WG data (h, barrier counter) uses ONLY relaxed agent-scope atomics
// (sc0 sc1 -> Infinity-Cache coherent) -- no __threadfence (which lowers to
// full-L2 writeback/invalidate and serialized the whole chip in R1).

#define SEQ 1024
#define NB  64
#define INF 512
#define RES 2048

typedef float    f32x4 __attribute__((ext_vector_type(4)));
typedef _Float16 f16x8 __attribute__((ext_vector_type(8)));

// ---------------------------------------------------------------------------
// Kernel B: U = X @ Win^T + bias   (M=65536, N=2048, K=512), U -> d_out states
// ---------------------------------------------------------------------------
__global__ __launch_bounds__(256) void xin_gemm(
    const float* __restrict__ X, const float* __restrict__ Win,
    const float* __restrict__ bias, float* __restrict__ U)
{
  __shared__ _Float16 lA[2][128][40];
  __shared__ _Float16 lB[2][128][40];

  const int tid  = threadIdx.x;
  const int lane = tid & 63;
  const int wv   = tid >> 6;
  const int wr   = wv >> 1;
  const int wc   = wv & 1;
  const int m0   = (blockIdx.x >> 4) * 128;
  const int n0   = (blockIdx.x & 15) * 128;

  const int srow = tid >> 1;
  const int sk   = (tid & 1) * 16;

  const int fr = lane & 15;
  const int fk = (lane >> 4) * 8;

  f32x4 acc[4][4] = {};
  float ra[16], rb[16];

  const float* xa_base = X   + (size_t)(m0 + srow) * INF + sk;
  const float* xb_base = Win + (size_t)(n0 + srow) * INF + sk;

#define LOADK(kt) do {                                                     \
    const float* pa = xa_base + (kt) * 32;                                 \
    const float* pb = xb_base + (kt) * 32;                                 \
    *(f32x4*)&ra[0]  = *(const f32x4*)(pa + 0);                            \
    *(f32x4*)&ra[4]  = *(const f32x4*)(pa + 4);                            \
    *(f32x4*)&ra[8]  = *(const f32x4*)(pa + 8);                            \
    *(f32x4*)&ra[12] = *(const f32x4*)(pa + 12);                           \
    *(f32x4*)&rb[0]  = *(const f32x4*)(pb + 0);                            \
    *(f32x4*)&rb[4]  = *(const f32x4*)(pb + 4);                            \
    *(f32x4*)&rb[8]  = *(const f32x4*)(pb + 8);                            \
    *(f32x4*)&rb[12] = *(const f32x4*)(pb + 12);                           \
  } while (0)

#define STOREK(buf) do {                                                   \
    f16x8 h0, h1;                                                          \
    _Pragma("unroll") for (int j = 0; j < 8; ++j) h0[j] = (_Float16)ra[j]; \
    _Pragma("unroll") for (int j = 0; j < 8; ++j) h1[j] = (_Float16)ra[8+j];\
    *(f16x8*)&lA[buf][srow][sk]     = h0;                                  \
    *(f16x8*)&lA[buf][srow][sk + 8] = h1;                                  \
    _Pragma("unroll") for (int j = 0; j < 8; ++j) h0[j] = (_Float16)rb[j]; \
    _Pragma("unroll") for (int j = 0; j < 8; ++j) h1[j] = (_Float16)rb[8+j];\
    *(f16x8*)&lB[buf][srow][sk]     = h0;                                  \
    *(f16x8*)&lB[buf][srow][sk + 8] = h1;                                  \
  } while (0)

#define COMPUTE(buf) do {                                                  \
    f16x8 af[4], bf[4];                                                    \
    _Pragma("unroll") for (int mt = 0; mt < 4; ++mt)                       \
      af[mt] = *(const f16x8*)&lA[buf][wr*64 + mt*16 + fr][fk];            \
    _Pragma("unroll") for (int nt = 0; nt < 4; ++nt)                       \
      bf[nt] = *(const f16x8*)&lB[buf][wc*64 + nt*16 + fr][fk];            \
    _Pragma("unroll") for (int mt = 0; mt < 4; ++mt)                       \
      _Pragma("unroll") for (int nt = 0; nt < 4; ++nt)                     \
        acc[mt][nt] = __builtin_amdgcn_mfma_f32_16x16x32_f16(              \
            af[mt], bf[nt], acc[mt][nt], 0, 0, 0);                         \
  } while (0)

  LOADK(0);
  STOREK(0);
  __syncthreads();

#pragma unroll 1
  for (int kt = 0; kt < 16; ++kt) {
    const int buf = kt & 1;
    if (kt < 15) LOADK(kt + 1);
    COMPUTE(buf);
    if (kt < 15) STOREK(buf ^ 1);
    __syncthreads();
  }

#pragma unroll
  for (int mt = 0; mt < 4; ++mt) {
    const int row = m0 + wr*64 + mt*16 + (lane >> 4) * 4;
#pragma unroll
    for (int nt = 0; nt < 4; ++nt) {
      const int col = n0 + wc*64 + nt*16 + fr;
      const float bv = bias[col];
#pragma unroll
      for (int i = 0; i < 4; ++i)
        U[(size_t)(row + i) * RES + col] = acc[mt][nt][i] + bv;
    }
  }
#undef LOADK
#undef STOREK
#undef COMPUTE
}

// ---------------------------------------------------------------------------
// Kernel C: persistent recurrence. 256 WGs x 512 thr, 1 WG/CU.
// WG = (batch-group bg: 16 batches) x (col-group cg: 32 res cols).
// 8 waves = 8 k-eighths; each wave computes BOTH 16-col tiles (one A-frag).
// Wave 0 reduces, applies tanh, stores states + fp16 h.
// Barrier: one monotonic counter per batch-group; arrive = atomicAdd,
// wait = spin(count >= 64*(s+1)) with s_sleep backoff. No fences.
// ---------------------------------------------------------------------------
#define WPAD 2056   // 2048 + 8 halfs pad

__global__ __launch_bounds__(512, 1) void esn_recur(
    const float* __restrict__ Whh, float* __restrict__ states,
    float* __restrict__ hn, _Float16* __restrict__ hbuf,
    unsigned* __restrict__ flags)
{
  __shared__ _Float16 Wl[32 * WPAD];    // 128.5 KB
  __shared__ f32x4    red[2][7][64];    // 14 KB

  const int tid  = threadIdx.x;
  const int lane = tid & 63;
  const int q    = tid >> 6;            // wave = k-eighth 0..7

  const int bid = blockIdx.x;
  const int xg  = bid & 7;
  const int bg  = xg >> 1;                        // batch group 0..3
  const int cg  = ((xg & 1) << 5) | (bid >> 3);   // col group 0..63 (bijective)
  const int b0  = bg * 16;
  const int c0  = cg * 32;

  // one-time: W_hh rows [c0, c0+32) -> LDS fp16
  {
    const int row = tid >> 4;
    const int ch  = tid & 15;
    const float* src = Whh + (size_t)(c0 + row) * RES + ch * 128;
    _Float16* dst = Wl + row * WPAD + ch * 128;
#pragma unroll 4
    for (int i = 0; i < 128; i += 4) {
      f32x4 v = *(const f32x4*)(src + i);
      dst[i + 0] = (_Float16)v.x;
      dst[i + 1] = (_Float16)v.y;
      dst[i + 2] = (_Float16)v.z;
      dst[i + 3] = (_Float16)v.w;
    }
  }
  __syncthreads();

  const int fr = lane & 15;
  const int fk = (lane >> 4) * 8;

  const _Float16* const wp0 = Wl + fr * WPAD + q * 256 + fk;
  const _Float16* const wp1 = wp0 + 16 * WPAD;

  _Float16* const hbuf0 = hbuf;
  _Float16* const hbuf1 = hbuf + (size_t)NB * RES;
  unsigned* const cnt = flags + bg * 64;   // 256B-separated counters

  for (int s = 0; s < SEQ; ++s) {
    f32x4 a0 = {0.f, 0.f, 0.f, 0.f}, a1 = {0.f, 0.f, 0.f, 0.f};

    float u[8];
    if (q == 0) {
      // prefetch private u = xin[s] slice; independent of h -> overlaps MFMA
      const float* up = states + (size_t)s * NB * RES;
#pragma unroll
      for (int t = 0; t < 8; ++t) {
        const int ct = t >> 2, i = t & 3;
        const int b  = b0 + (lane >> 4) * 4 + i;
        u[t] = up[(size_t)b * RES + c0 + ct * 16 + fr];
      }
    }

    if (s > 0) {
      const _Float16* hp = ((s & 1) ? hbuf0 : hbuf1)
                         + (size_t)(b0 + fr) * RES + q * 256 + fk;
#pragma unroll
      for (int ks = 0; ks < 8; ++ks) {
        union { unsigned long long w[2]; f16x8 v; } au;
        au.w[0] = __hip_atomic_load((const unsigned long long*)(hp + ks * 32),
                                    __ATOMIC_RELAXED, __HIP_MEMORY_SCOPE_AGENT);
        au.w[1] = __hip_atomic_load((const unsigned long long*)(hp + ks * 32 + 4),
                                    __ATOMIC_RELAXED, __HIP_MEMORY_SCOPE_AGENT);
        const f16x8 w0 = *(const f16x8*)(wp0 + ks * 32);
        const f16x8 w1 = *(const f16x8*)(wp1 + ks * 32);
        a0 = __builtin_amdgcn_mfma_f32_16x16x32_f16(au.v, w0, a0, 0, 0, 0);
        a1 = __builtin_amdgcn_mfma_f32_16x16x32_f16(au.v, w1, a1, 0, 0, 0);
      }
    }

    if (q > 0) { red[0][q - 1][lane] = a0; red[1][q - 1][lane] = a1; }
    __syncthreads();

    if (q == 0) {
#pragma unroll
      for (int j = 0; j < 7; ++j) { a0 += red[0][j][lane]; a1 += red[1][j][lane]; }

      float* up = states + (size_t)s * NB * RES;
      _Float16* hc = (s & 1) ? hbuf1 : hbuf0;
      unsigned short* hc16 = (unsigned short*)hc;
#pragma unroll
      for (int t = 0; t < 8; ++t) {
        const int ct = t >> 2, i = t & 3;
        const int b   = b0 + (lane >> 4) * 4 + i;
        const int col = c0 + ct * 16 + fr;
        const size_t off = (size_t)b * RES + col;
        const float v = tanhf(u[t] + (t < 4 ? a0[i] : a1[i]));
        up[off] = v;                                    // states[s] (private)
        const _Float16 vh = (_Float16)v;
        __hip_atomic_store(&hc16[off], __builtin_bit_cast(unsigned short, vh),
                           __ATOMIC_RELAXED, __HIP_MEMORY_SCOPE_AGENT);
        if (s == SEQ - 1) hn[off] = v;
      }
      // ensure this wave's h stores reached the coherence point, then arrive
      asm volatile("s_waitcnt vmcnt(0)" ::: "memory");
      if (lane == 0) {
        __hip_atomic_fetch_add(cnt, 1u, __ATOMIC_RELAXED, __HIP_MEMORY_SCOPE_AGENT);
        const unsigned target = 64u * (unsigned)(s + 1);
        while (__hip_atomic_load(cnt, __ATOMIC_RELAXED, __HIP_MEMORY_SCOPE_AGENT) < target)
          __builtin_amdgcn_s_sleep(2);
      }
    }
    __syncthreads();   // releases all waves; h loads of step s+1 follow
  }
}

// ---------------------------------------------------------------------------
extern "C" void kernel_launch(void* const* d_in, const int* in_sizes, int n_in,
                              void* d_out, int out_size, void* d_ws, size_t ws_size,
                              hipStream_t stream) {
  const float* x    = (const float*)d_in[0];   // [1024][64][512]
  const float* W_in = (const float*)d_in[1];   // [2048][512]
  const float* W_hh = (const float*)d_in[2];   // [2048][2048]
  const float* bias = (const float*)d_in[3];   // [2048]

  float* states = (float*)d_out;                        // [1024][64][2048]
  float* hn     = states + (size_t)SEQ * NB * RES;      // [64][2048]

  _Float16* hbuf  = (_Float16*)d_ws;                    // 2 x [64][2048] fp16
  unsigned* flags = (unsigned*)((char*)d_ws + (size_t)2 * NB * RES * sizeof(_Float16));

  hipMemsetAsync(flags, 0, 256 * sizeof(unsigned), stream);

  xin_gemm<<<dim3(512 * 16), dim3(256), 0, stream>>>(x, W_in, bias, states);
  esn_recur<<<dim3(256), dim3(512), 0, stream>>>(W_hh, states, hn, hbuf, flags);
}

// Round 3
// 7108.939 us; speedup vs baseline: 11.9237x; 1.0641x over previous
//
#include <hip/hip_runtime.h>
#include <hip/hip_bf16.h>

// ESN forward: states[s] = tanh(x[s] @ W_in^T + b + h_{s-1} @ W_hh^T)
// SEQ=1024, BATCH=64, IN=512, RES=2048, all fp32 in/out.
// fp16 MFMA; W_hh resident in LDS (persistent kernel, 1 WG/CU).
// Cross-WG data (h, flags) uses ONLY relaxed agent-scope atomics (IF$-coherent,
// no cache-maintenance). R3: contention-free padded per-WG flags polled by a
// dedicated wave with wave-wide gathers (R2's single atomicAdd counter
// serialized 64 RMWs/step at the coherence point); split epilogue across
// waves 0/1; fast tanh.

#define SEQ 1024
#define NB  64
#define INF 512
#define RES 2048

typedef float    f32x4 __attribute__((ext_vector_type(4)));
typedef _Float16 f16x8 __attribute__((ext_vector_type(8)));

__device__ __forceinline__ float fast_tanh(float x) {
  // tanh(x) = 1 - 2/(1+e^{2x}); exact saturation at +/-inf, ~1e-6 abs err
  const float e = __expf(2.0f * x);
  return 1.0f - 2.0f * __builtin_amdgcn_rcpf(1.0f + e);
}

// ---------------------------------------------------------------------------
// Kernel B: U = X @ Win^T + bias   (M=65536, N=2048, K=512), U -> d_out states
// ---------------------------------------------------------------------------
__global__ __launch_bounds__(256) void xin_gemm(
    const float* __restrict__ X, const float* __restrict__ Win,
    const float* __restrict__ bias, float* __restrict__ U)
{
  __shared__ _Float16 lA[2][128][40];
  __shared__ _Float16 lB[2][128][40];

  const int tid  = threadIdx.x;
  const int lane = tid & 63;
  const int wv   = tid >> 6;
  const int wr   = wv >> 1;
  const int wc   = wv & 1;
  const int m0   = (blockIdx.x >> 4) * 128;
  const int n0   = (blockIdx.x & 15) * 128;

  const int srow = tid >> 1;
  const int sk   = (tid & 1) * 16;

  const int fr = lane & 15;
  const int fk = (lane >> 4) * 8;

  f32x4 acc[4][4] = {};
  float ra[16], rb[16];

  const float* xa_base = X   + (size_t)(m0 + srow) * INF + sk;
  const float* xb_base = Win + (size_t)(n0 + srow) * INF + sk;

#define LOADK(kt) do {                                                     \
    const float* pa = xa_base + (kt) * 32;                                 \
    const float* pb = xb_base + (kt) * 32;                                 \
    *(f32x4*)&ra[0]  = *(const f32x4*)(pa + 0);                            \
    *(f32x4*)&ra[4]  = *(const f32x4*)(pa + 4);                            \
    *(f32x4*)&ra[8]  = *(const f32x4*)(pa + 8);                            \
    *(f32x4*)&ra[12] = *(const f32x4*)(pa + 12);                           \
    *(f32x4*)&rb[0]  = *(const f32x4*)(pb + 0);                            \
    *(f32x4*)&rb[4]  = *(const f32x4*)(pb + 4);                            \
    *(f32x4*)&rb[8]  = *(const f32x4*)(pb + 8);                            \
    *(f32x4*)&rb[12] = *(const f32x4*)(pb + 12);                           \
  } while (0)

#define STOREK(buf) do {                                                   \
    f16x8 h0, h1;                                                          \
    _Pragma("unroll") for (int j = 0; j < 8; ++j) h0[j] = (_Float16)ra[j]; \
    _Pragma("unroll") for (int j = 0; j < 8; ++j) h1[j] = (_Float16)ra[8+j];\
    *(f16x8*)&lA[buf][srow][sk]     = h0;                                  \
    *(f16x8*)&lA[buf][srow][sk + 8] = h1;                                  \
    _Pragma("unroll") for (int j = 0; j < 8; ++j) h0[j] = (_Float16)rb[j]; \
    _Pragma("unroll") for (int j = 0; j < 8; ++j) h1[j] = (_Float16)rb[8+j];\
    *(f16x8*)&lB[buf][srow][sk]     = h0;                                  \
    *(f16x8*)&lB[buf][srow][sk + 8] = h1;                                  \
  } while (0)

#define COMPUTE(buf) do {                                                  \
    f16x8 af[4], bf[4];                                                    \
    _Pragma("unroll") for (int mt = 0; mt < 4; ++mt)                       \
      af[mt] = *(const f16x8*)&lA[buf][wr*64 + mt*16 + fr][fk];            \
    _Pragma("unroll") for (int nt = 0; nt < 4; ++nt)                       \
      bf[nt] = *(const f16x8*)&lB[buf][wc*64 + nt*16 + fr][fk];            \
    _Pragma("unroll") for (int mt = 0; mt < 4; ++mt)                       \
      _Pragma("unroll") for (int nt = 0; nt < 4; ++nt)                     \
        acc[mt][nt] = __builtin_amdgcn_mfma_f32_16x16x32_f16(              \
            af[mt], bf[nt], acc[mt][nt], 0, 0, 0);                         \
  } while (0)

  LOADK(0);
  STOREK(0);
  __syncthreads();

#pragma unroll 1
  for (int kt = 0; kt < 16; ++kt) {
    const int buf = kt & 1;
    if (kt < 15) LOADK(kt + 1);
    COMPUTE(buf);
    if (kt < 15) STOREK(buf ^ 1);
    __syncthreads();
  }

#pragma unroll
  for (int mt = 0; mt < 4; ++mt) {
    const int row = m0 + wr*64 + mt*16 + (lane >> 4) * 4;
#pragma unroll
    for (int nt = 0; nt < 4; ++nt) {
      const int col = n0 + wc*64 + nt*16 + fr;
      const float bv = bias[col];
#pragma unroll
      for (int i = 0; i < 4; ++i)
        U[(size_t)(row + i) * RES + col] = acc[mt][nt][i] + bv;
    }
  }
#undef LOADK
#undef STOREK
#undef COMPUTE
}

// ---------------------------------------------------------------------------
// Kernel C: persistent recurrence. 256 WGs x 512 thr, 1 WG/CU.
// WG = (batch-group bg: 16 batches) x (col-group cg: 32 res cols).
// 8 waves = 8 k-eighths; each wave computes BOTH 16-col tiles.
// Epilogue split: wave0 -> col tile 0, wave1 -> col tile 1 (reduce via LDS).
// Barrier: per-WG 128B-padded flag cells (2 per WG: one per epilogue wave),
// plain relaxed stores; wave2 polls all 128 cells of the batch-group with two
// wave-wide gathers + __all. No RMW, no fences.
// ---------------------------------------------------------------------------
#define WPAD 2056   // 2048 + 8 halfs pad

__global__ __launch_bounds__(512, 1) void esn_recur(
    const float* __restrict__ Whh, float* __restrict__ states,
    float* __restrict__ hn, _Float16* __restrict__ hbuf,
    unsigned* __restrict__ flags)
{
  __shared__ _Float16 Wl[32 * WPAD];    // 128.5 KB
  __shared__ f32x4    red0[8][64];      // 8 KB
  __shared__ f32x4    red1[8][64];      // 8 KB

  const int tid  = threadIdx.x;
  const int lane = tid & 63;
  const int wv   = tid >> 6;            // wave id = k-eighth q
  const int q    = wv;

  const int bid = blockIdx.x;
  const int xg  = bid & 7;
  const int bg  = xg >> 1;                        // batch group 0..3
  const int cg  = ((xg & 1) << 5) | (bid >> 3);   // col group 0..63 (bijective)
  const int b0  = bg * 16;
  const int c0  = cg * 32;

  // one-time: W_hh rows [c0, c0+32) -> LDS fp16
  {
    const int row = tid >> 4;
    const int ch  = tid & 15;
    const float* src = Whh + (size_t)(c0 + row) * RES + ch * 128;
    _Float16* dst = Wl + row * WPAD + ch * 128;
#pragma unroll 4
    for (int i = 0; i < 128; i += 4) {
      f32x4 v = *(const f32x4*)(src + i);
      dst[i + 0] = (_Float16)v.x;
      dst[i + 1] = (_Float16)v.y;
      dst[i + 2] = (_Float16)v.z;
      dst[i + 3] = (_Float16)v.w;
    }
  }
  __syncthreads();

  const int fr = lane & 15;
  const int fk = (lane >> 4) * 8;

  const _Float16* const wp0 = Wl + fr * WPAD + q * 256 + fk;
  const _Float16* const wp1 = wp0 + 16 * WPAD;

  _Float16* const hbuf0 = hbuf;
  _Float16* const hbuf1 = hbuf + (size_t)NB * RES;
  unsigned* const fb = flags + bg * (128 * 32);   // 128 cells x 128B per group

  for (int s = 0; s < SEQ; ++s) {
    f32x4 a0 = {0.f, 0.f, 0.f, 0.f}, a1 = {0.f, 0.f, 0.f, 0.f};

    float u[4];
    if (wv < 2) {
      // prefetch private u = xin[s] slice for this wave's col tile
      const float* up = states + (size_t)s * NB * RES;
      const int col = c0 + wv * 16 + fr;
#pragma unroll
      for (int i = 0; i < 4; ++i) {
        const int b = b0 + (lane >> 4) * 4 + i;
        u[i] = up[(size_t)b * RES + col];
      }
    }

    if (s > 0) {
      const _Float16* hp = ((s & 1) ? hbuf0 : hbuf1)
                         + (size_t)(b0 + fr) * RES + q * 256 + fk;
#pragma unroll
      for (int ks = 0; ks < 8; ++ks) {
        union { unsigned long long w[2]; f16x8 v; } au;
        au.w[0] = __hip_atomic_load((const unsigned long long*)(hp + ks * 32),
                                    __ATOMIC_RELAXED, __HIP_MEMORY_SCOPE_AGENT);
        au.w[1] = __hip_atomic_load((const unsigned long long*)(hp + ks * 32 + 4),
                                    __ATOMIC_RELAXED, __HIP_MEMORY_SCOPE_AGENT);
        const f16x8 w0 = *(const f16x8*)(wp0 + ks * 32);
        const f16x8 w1 = *(const f16x8*)(wp1 + ks * 32);
        a0 = __builtin_amdgcn_mfma_f32_16x16x32_f16(au.v, w0, a0, 0, 0, 0);
        a1 = __builtin_amdgcn_mfma_f32_16x16x32_f16(au.v, w1, a1, 0, 0, 0);
      }
    }

    red0[q][lane] = a0;
    red1[q][lane] = a1;
    __syncthreads();

    if (wv < 2) {
      const f32x4 (* __restrict__ rp)[64] = wv ? red1 : red0;
      f32x4 acc = rp[0][lane];
#pragma unroll
      for (int j = 1; j < 8; ++j) acc += rp[j][lane];

      float* up = states + (size_t)s * NB * RES;
      unsigned short* hc16 = (unsigned short*)((s & 1) ? hbuf1 : hbuf0);
      const int col = c0 + wv * 16 + fr;
#pragma unroll
      for (int i = 0; i < 4; ++i) {
        const int b = b0 + (lane >> 4) * 4 + i;
        const size_t off = (size_t)b * RES + col;
        const float v = fast_tanh(u[i] + acc[i]);
        up[off] = v;                                    // states[s] (private)
        const _Float16 vh = (_Float16)v;
        __hip_atomic_store(&hc16[off], __builtin_bit_cast(unsigned short, vh),
                           __ATOMIC_RELAXED, __HIP_MEMORY_SCOPE_AGENT);
        if (s == SEQ - 1) hn[off] = v;
      }
      // drain our h stores to the coherence point, then raise our flag cell
      asm volatile("s_waitcnt vmcnt(0)" ::: "memory");
      if (lane == 0)
        __hip_atomic_store(fb + (wv * 64 + cg) * 32, (unsigned)(s + 1),
                           __ATOMIC_RELAXED, __HIP_MEMORY_SCOPE_AGENT);
    } else if (wv == 2) {
      // dedicated poller: two wave-wide gathers cover all 128 group flags
      const unsigned tgt = (unsigned)(s + 1);
      for (;;) {
        const unsigned va = __hip_atomic_load(fb + lane * 32,
                              __ATOMIC_RELAXED, __HIP_MEMORY_SCOPE_AGENT);
        const unsigned vb = __hip_atomic_load(fb + (64 + lane) * 32,
                              __ATOMIC_RELAXED, __HIP_MEMORY_SCOPE_AGENT);
        if (__all((va >= tgt) & (vb >= tgt))) break;
      }
    }
    __syncthreads();   // releases all waves; h loads of step s+1 follow
  }
}

// ---------------------------------------------------------------------------
extern "C" void kernel_launch(void* const* d_in, const int* in_sizes, int n_in,
                              void* d_out, int out_size, void* d_ws, size_t ws_size,
                              hipStream_t stream) {
  const float* x    = (const float*)d_in[0];   // [1024][64][512]
  const float* W_in = (const float*)d_in[1];   // [2048][512]
  const float* W_hh = (const float*)d_in[2];   // [2048][2048]
  const float* bias = (const float*)d_in[3];   // [2048]

  float* states = (float*)d_out;                        // [1024][64][2048]
  float* hn     = states + (size_t)SEQ * NB * RES;      // [64][2048]

  _Float16* hbuf  = (_Float16*)d_ws;                    // 2 x [64][2048] fp16
  unsigned* flags = (unsigned*)((char*)d_ws + (size_t)2 * NB * RES * sizeof(_Float16));

  // 4 groups x 128 cells x 128B
  hipMemsetAsync(flags, 0, (size_t)4 * 128 * 32 * sizeof(unsigned), stream);

  xin_gemm<<<dim3(512 * 16), dim3(256), 0, stream>>>(x, W_in, bias, states);
  esn_recur<<<dim3(256), dim3(512), 0, stream>>>(W_hh, states, hn, hbuf, flags);
}

// Round 4
// 6678.790 us; speedup vs baseline: 12.6917x; 1.0644x over previous
//
#include <hip/hip_runtime.h>
#include <hip/hip_bf16.h>

// ESN forward: states[s] = tanh(x[s] @ W_in^T + b + h_{s-1} @ W_hh^T)
// SEQ=1024, BATCH=64, IN=512, RES=2048, fp32 in/out.
// R4: W_hh in VGPRs (was LDS: 8-way bank conflicts + 128KB/step stream);
// h exchanged through a 16-slot NaN-sentinel ring in ws -- consumers poll the
// data itself (fuses flag+detect+load into one IF$ RT). Group barrier only
// every 8 steps (bounds skew < ring depth; slots re-poisoned there, drained
// before flag raise). All cross-WG traffic relaxed agent-scope (IF$-coherent,
// no cache maintenance).

#define SEQ  1024
#define NB   64
#define INF  512
#define RES  2048
#define RING 16

typedef float    f32x4 __attribute__((ext_vector_type(4)));
typedef _Float16 f16x8 __attribute__((ext_vector_type(8)));

__device__ __forceinline__ float fast_tanh(float x) {
  const float e = __expf(2.0f * x);
  return 1.0f - 2.0f * __builtin_amdgcn_rcpf(1.0f + e);
}

// ---------------------------------------------------------------------------
// Kernel B: U = X @ Win^T + bias   (M=65536, N=2048, K=512), U -> d_out states
// ---------------------------------------------------------------------------
__global__ __launch_bounds__(256) void xin_gemm(
    const float* __restrict__ X, const float* __restrict__ Win,
    const float* __restrict__ bias, float* __restrict__ U)
{
  __shared__ _Float16 lA[2][128][40];
  __shared__ _Float16 lB[2][128][40];

  const int tid  = threadIdx.x;
  const int lane = tid & 63;
  const int wv   = tid >> 6;
  const int wr   = wv >> 1;
  const int wc   = wv & 1;
  const int m0   = (blockIdx.x >> 4) * 128;
  const int n0   = (blockIdx.x & 15) * 128;

  const int srow = tid >> 1;
  const int sk   = (tid & 1) * 16;

  const int fr = lane & 15;
  const int fk = (lane >> 4) * 8;

  f32x4 acc[4][4] = {};
  float ra[16], rb[16];

  const float* xa_base = X   + (size_t)(m0 + srow) * INF + sk;
  const float* xb_base = Win + (size_t)(n0 + srow) * INF + sk;

#define LOADK(kt) do {                                                     \
    const float* pa = xa_base + (kt) * 32;                                 \
    const float* pb = xb_base + (kt) * 32;                                 \
    *(f32x4*)&ra[0]  = *(const f32x4*)(pa + 0);                            \
    *(f32x4*)&ra[4]  = *(const f32x4*)(pa + 4);                            \
    *(f32x4*)&ra[8]  = *(const f32x4*)(pa + 8);                            \
    *(f32x4*)&ra[12] = *(const f32x4*)(pa + 12);                           \
    *(f32x4*)&rb[0]  = *(const f32x4*)(pb + 0);                            \
    *(f32x4*)&rb[4]  = *(const f32x4*)(pb + 4);                            \
    *(f32x4*)&rb[8]  = *(const f32x4*)(pb + 8);                            \
    *(f32x4*)&rb[12] = *(const f32x4*)(pb + 12);                           \
  } while (0)

#define STOREK(buf) do {                                                   \
    f16x8 h0, h1;                                                          \
    _Pragma("unroll") for (int j = 0; j < 8; ++j) h0[j] = (_Float16)ra[j]; \
    _Pragma("unroll") for (int j = 0; j < 8; ++j) h1[j] = (_Float16)ra[8+j];\
    *(f16x8*)&lA[buf][srow][sk]     = h0;                                  \
    *(f16x8*)&lA[buf][srow][sk + 8] = h1;                                  \
    _Pragma("unroll") for (int j = 0; j < 8; ++j) h0[j] = (_Float16)rb[j]; \
    _Pragma("unroll") for (int j = 0; j < 8; ++j) h1[j] = (_Float16)rb[8+j];\
    *(f16x8*)&lB[buf][srow][sk]     = h0;                                  \
    *(f16x8*)&lB[buf][srow][sk + 8] = h1;                                  \
  } while (0)

#define COMPUTE(buf) do {                                                  \
    f16x8 af[4], bf[4];                                                    \
    _Pragma("unroll") for (int mt = 0; mt < 4; ++mt)                       \
      af[mt] = *(const f16x8*)&lA[buf][wr*64 + mt*16 + fr][fk];            \
    _Pragma("unroll") for (int nt = 0; nt < 4; ++nt)                       \
      bf[nt] = *(const f16x8*)&lB[buf][wc*64 + nt*16 + fr][fk];            \
    _Pragma("unroll") for (int mt = 0; mt < 4; ++mt)                       \
      _Pragma("unroll") for (int nt = 0; nt < 4; ++nt)                     \
        acc[mt][nt] = __builtin_amdgcn_mfma_f32_16x16x32_f16(              \
            af[mt], bf[nt], acc[mt][nt], 0, 0, 0);                         \
  } while (0)

  LOADK(0);
  STOREK(0);
  __syncthreads();

#pragma unroll 1
  for (int kt = 0; kt < 16; ++kt) {
    const int buf = kt & 1;
    if (kt < 15) LOADK(kt + 1);
    COMPUTE(buf);
    if (kt < 15) STOREK(buf ^ 1);
    __syncthreads();
  }

#pragma unroll
  for (int mt = 0; mt < 4; ++mt) {
    const int row = m0 + wr*64 + mt*16 + (lane >> 4) * 4;
#pragma unroll
    for (int nt = 0; nt < 4; ++nt) {
      const int col = n0 + wc*64 + nt*16 + fr;
      const float bv = bias[col];
#pragma unroll
      for (int i = 0; i < 4; ++i)
        U[(size_t)(row + i) * RES + col] = acc[mt][nt][i] + bv;
    }
  }
#undef LOADK
#undef STOREK
#undef COMPUTE
}

// ---------------------------------------------------------------------------
// Kernel C: persistent recurrence. 256 WGs x 512 thr, 1 WG/CU.
// WG = (batch-group bg: 16 batches) x (col-group cg: 32 res cols).
// 8 waves = 8 K-eighths; W frags in VGPRs (16 x f16x8 per thread).
// h ring: RING slots fp16 [NB][RES]; slot init/poison = 0x7F7F (fp16 NaN).
// Consumer at step s polls slot (s-1)&15 until no NaN (pk_add NaN-propagate).
// Group barrier every 8 steps (flags + wave-2 poller); producers poison the
// 8 stale slots there, drain, then raise flags.
// ---------------------------------------------------------------------------
__global__ __launch_bounds__(512, 1) void esn_recur(
    const float* __restrict__ Whh, float* __restrict__ states,
    float* __restrict__ hn, _Float16* __restrict__ ring,
    unsigned* __restrict__ flags)
{
  __shared__ f32x4 red0[8][64];     // 8 KB
  __shared__ f32x4 red1[8][64];     // 8 KB

  const int tid  = threadIdx.x;
  const int lane = tid & 63;
  const int wv   = tid >> 6;        // wave = K-eighth q
  const int q    = wv;

  const int bid = blockIdx.x;
  const int xg  = bid & 7;
  const int bg  = xg >> 1;                        // batch group 0..3
  const int cg  = ((xg & 1) << 5) | (bid >> 3);   // col group 0..63
  const int b0  = bg * 16;
  const int c0  = cg * 32;

  const int fr = lane & 15;
  const int fk = (lane >> 4) * 8;

  // ---- one-time: W_hh fragments -> VGPRs (16 x f16x8 = 64 VGPR) ----
  f16x8 wf[2][8];
#pragma unroll
  for (int ct = 0; ct < 2; ++ct) {
#pragma unroll
    for (int ks = 0; ks < 8; ++ks) {
      const float* wsrc = Whh + (size_t)(c0 + ct*16 + fr) * RES
                        + q*256 + ks*32 + fk;
      const f32x4 w0 = *(const f32x4*)(wsrc);
      const f32x4 w1 = *(const f32x4*)(wsrc + 4);
      f16x8 f;
#pragma unroll
      for (int j = 0; j < 4; ++j) { f[j] = (_Float16)w0[j]; f[4+j] = (_Float16)w1[j]; }
      wf[ct][ks] = f;
    }
  }

  unsigned* const fb = flags + bg * (128 * 32);   // 128 cells x 128B per group

  for (int s = 0; s < SEQ; ++s) {
    f32x4 a0 = {0.f, 0.f, 0.f, 0.f}, a1 = {0.f, 0.f, 0.f, 0.f};

    float u[4];
    if (wv < 2) {
      const float* up = states + (size_t)s * NB * RES;
      const int col = c0 + wv * 16 + fr;
#pragma unroll
      for (int i = 0; i < 4; ++i)
        u[i] = up[(size_t)(b0 + (lane >> 4) * 4 + i) * RES + col];
    }

    if (s > 0) {
      const _Float16* hp = ring + (size_t)((s - 1) & (RING - 1)) * NB * RES
                         + (size_t)(b0 + fr) * RES + q * 256 + fk;
      f16x8 hv[8];
      for (;;) {
#pragma unroll
        for (int ks = 0; ks < 8; ++ks) {
          union { unsigned long long w[2]; f16x8 v; } au;
          au.w[0] = __hip_atomic_load((const unsigned long long*)(hp + ks*32),
                                      __ATOMIC_RELAXED, __HIP_MEMORY_SCOPE_AGENT);
          au.w[1] = __hip_atomic_load((const unsigned long long*)(hp + ks*32 + 4),
                                      __ATOMIC_RELAXED, __HIP_MEMORY_SCOPE_AGENT);
          hv[ks] = au.v;
        }
        // NaN sentinel detect: pk_add propagates NaN; legit |sum| <= 8
        f16x8 t0 = hv[0] + hv[1], t1 = hv[2] + hv[3];
        f16x8 t2 = hv[4] + hv[5], t3 = hv[6] + hv[7];
        f16x8 ss = (t0 + t1) + (t2 + t3);
        union { f16x8 v; unsigned w[4]; } su; su.v = ss;
        unsigned bad = 0;
#pragma unroll
        for (int j = 0; j < 4; ++j) {
          bad |= ((su.w[j] & 0x7C00u) == 0x7C00u);
          bad |= (((su.w[j] >> 16) & 0x7C00u) == 0x7C00u);
        }
        if (!__any(bad)) break;
      }
#pragma unroll
      for (int ks = 0; ks < 8; ++ks) {
        a0 = __builtin_amdgcn_mfma_f32_16x16x32_f16(hv[ks], wf[0][ks], a0, 0, 0, 0);
        a1 = __builtin_amdgcn_mfma_f32_16x16x32_f16(hv[ks], wf[1][ks], a1, 0, 0, 0);
      }
    }

    red0[q][lane] = a0;
    red1[q][lane] = a1;
    __syncthreads();

    const bool barrier_step = ((s & 7) == 7) && (s != SEQ - 1);

    if (wv < 2) {
      const f32x4 (* __restrict__ rp)[64] = wv ? red1 : red0;
      f32x4 acc = rp[0][lane];
#pragma unroll
      for (int j = 1; j < 8; ++j) acc += rp[j][lane];

      float* up = states + (size_t)s * NB * RES;
      unsigned short* hc16 = (unsigned short*)(ring
                           + (size_t)(s & (RING - 1)) * NB * RES);
      const int col = c0 + wv * 16 + fr;
#pragma unroll
      for (int i = 0; i < 4; ++i) {
        const int b = b0 + (lane >> 4) * 4 + i;
        const size_t off = (size_t)b * RES + col;
        const float v = fast_tanh(u[i] + acc[i]);
        up[off] = v;
        const _Float16 vh = (_Float16)v;
        __hip_atomic_store(&hc16[off], __builtin_bit_cast(unsigned short, vh),
                           __ATOMIC_RELAXED, __HIP_MEMORY_SCOPE_AGENT);
        if (s == SEQ - 1) hn[off] = v;
      }
      asm volatile("s_waitcnt vmcnt(0)" ::: "memory");   // h_s in IF$

      if (barrier_step) {
        // poison stale slots (s-15..s-8) == (s+1..s+8) mod 16 (own slice only)
#pragma unroll
        for (int d = 1; d <= 8; ++d) {
          unsigned short* pz = (unsigned short*)(ring
                             + (size_t)((s + d) & (RING - 1)) * NB * RES);
#pragma unroll
          for (int i = 0; i < 4; ++i) {
            const size_t off = (size_t)(b0 + (lane >> 4) * 4 + i) * RES + col;
            __hip_atomic_store(&pz[off], (unsigned short)0x7F7Fu,
                               __ATOMIC_RELAXED, __HIP_MEMORY_SCOPE_AGENT);
          }
        }
        asm volatile("s_waitcnt vmcnt(0)" ::: "memory"); // poison in IF$
        if (lane == 0)
          __hip_atomic_store(fb + (wv * 64 + cg) * 32, (unsigned)((s >> 3) + 1),
                             __ATOMIC_RELAXED, __HIP_MEMORY_SCOPE_AGENT);
      }
    } else if (wv == 2 && barrier_step) {
      const unsigned tgt = (unsigned)((s >> 3) + 1);
      for (;;) {
        const unsigned va = __hip_atomic_load(fb + lane * 32,
                              __ATOMIC_RELAXED, __HIP_MEMORY_SCOPE_AGENT);
        const unsigned vb = __hip_atomic_load(fb + (64 + lane) * 32,
                              __ATOMIC_RELAXED, __HIP_MEMORY_SCOPE_AGENT);
        if (__all((va >= tgt) & (vb >= tgt))) break;
      }
    }
    __syncthreads();
  }
}

// ---------------------------------------------------------------------------
extern "C" void kernel_launch(void* const* d_in, const int* in_sizes, int n_in,
                              void* d_out, int out_size, void* d_ws, size_t ws_size,
                              hipStream_t stream) {
  const float* x    = (const float*)d_in[0];
  const float* W_in = (const float*)d_in[1];
  const float* W_hh = (const float*)d_in[2];
  const float* bias = (const float*)d_in[3];

  float* states = (float*)d_out;                        // [1024][64][2048]
  float* hn     = states + (size_t)SEQ * NB * RES;      // [64][2048]

  _Float16* ring  = (_Float16*)d_ws;                    // RING x [64][2048] fp16
  unsigned* flags = (unsigned*)((char*)d_ws
                  + (size_t)RING * NB * RES * sizeof(_Float16));

  // sentinel-init ring (0x7F7F = fp16 NaN), zero flags
  hipMemsetAsync(ring, 0x7F, (size_t)RING * NB * RES * sizeof(_Float16), stream);
  hipMemsetAsync(flags, 0, (size_t)4 * 128 * 32 * sizeof(unsigned), stream);

  xin_gemm<<<dim3(512 * 16), dim3(256), 0, stream>>>(x, W_in, bias, states);
  esn_recur<<<dim3(256), dim3(512), 0, stream>>>(W_hh, states, hn, ring, flags);
}